// Round 4
// baseline (114.563 us; speedup 1.0000x reference)
//
#include <hip/hip_runtime.h>

// Problem constants
#define Bq 32
#define Sq 2048
#define Dq 128
#define Tq 8
#define Mq (Bq * Sq)   // 65536 rows

typedef __attribute__((ext_vector_type(8))) short bf16x8;
typedef __attribute__((ext_vector_type(8))) unsigned short u16x8;
typedef __attribute__((ext_vector_type(4))) float f32x4;

static __device__ __forceinline__ unsigned short f2bf(float f) {
    unsigned int u = __float_as_uint(f);
    unsigned int r = (u + 0x7FFFu + ((u >> 16) & 1u)) >> 16;
    return (unsigned short)r;
}

// ---------------------------------------------------------------------------
// Kernel 1 (v3): W [T,D,D] fp32 -> bf16 in MFMA B-fragment order.
// 64 blocks, one 16-row (t,n) group each = one contiguous 4KB slice of wsw.
// Reads fully coalesced (16 threads x 8 consecutive floats per row), writes
// fully coalesced (one 16B u16x8 per thread).
//   flat chunk = ((t*8+n)*4+kk)*64+lane  <-  W[16*(t*8+n) + (lane&15)]
//                                             [kk*32+(lane>>4)*8 .. +8)
// ---------------------------------------------------------------------------
__global__ __launch_bounds__(256) void prep_kernel(const float* __restrict__ W,
                                                   unsigned short* __restrict__ wsw) {
    __shared__ unsigned short lds[16][132];   // 132-short stride breaks bank alias
    int tid = threadIdx.x;
    int b = blockIdx.x;                        // 64 blocks = (t,n) pairs
    int rl = tid >> 4;                         // local row 0..15
    int c0 = (tid & 15) * 8;                   // 8 floats per thread
    const float4* src = reinterpret_cast<const float4*>(W + ((size_t)b * 16 + rl) * 128 + c0);
    #pragma unroll
    for (int q = 0; q < 2; q++) {
        float4 v = src[q];
        lds[rl][c0 + q * 4 + 0] = f2bf(v.x);
        lds[rl][c0 + q * 4 + 1] = f2bf(v.y);
        lds[rl][c0 + q * 4 + 2] = f2bf(v.z);
        lds[rl][c0 + q * 4 + 3] = f2bf(v.w);
    }
    __syncthreads();
    int lane = tid & 63;
    int kk   = tid >> 6;                       // 0..3
    int e    = lane & 15;
    int d    = kk * 32 + (lane >> 4) * 8;
    u16x8* dst = reinterpret_cast<u16x8*>(wsw) + (size_t)b * 256 + tid;
    *dst = *reinterpret_cast<const u16x8*>(&lds[e][d]);
}

// ---------------------------------------------------------------------------
// Kernel 2 (fused), 64-row tiles, 1024 blocks.
// Round-3 lesson (VGPR_Count=88 vs ~140 live set written): the compiler SANK
// the register prefetches to their uses to cut pressure, defeating every
// ILP-based latency plan -> latency-bound (MfmaUtil 13%). Round-4 fix:
// shrink per-wave state so there's no pressure to sink, and cover residual
// latency with TLP instead of ILP:
//   - wave tile 32 rows x 64 cols (2x2 waves): a[2][4]=32, o[2][4]=32,
//     bf[2][4]=32, y[2]=8 -> ~120 VGPR live.
//   - __launch_bounds__(256,4): hard 128-VGPR cap (spill-free by design),
//     4 blocks/CU resident (grid gives exactly 4/CU) = 4 waves/SIMD.
//     Per n-step cover ~110cy x 4-way TLP > L2 latency.
//   phase A: stage x -> bf16 LDS (4 threads/row, fp32 in registers),
//            fp32 p-dots + |x|^2 inline, quad shuffle-reduce, softmax->simT.
//   phase B: MFMA GEMM vs pre-swizzled W, 1-step B prefetch, bias in the
//            MFMA C-operand, s_setprio around the MFMA cluster.
//   epilogue: out = x + sum_t sim*(y+bias); nontemporal on both sides.
// ---------------------------------------------------------------------------
__global__ __launch_bounds__(256, 4) void main_kernel(const float* __restrict__ x,
                                                      const unsigned short* __restrict__ wsw,
                                                      const float* __restrict__ bx,
                                                      const float* __restrict__ p,
                                                      float* __restrict__ out) {
    __shared__ unsigned short xs[64][136];   // +16B pad: row stride 272B (16B-aligned)
    __shared__ float simT[Tq][64];
    __shared__ float bxl[Tq][128];
    __shared__ float4 p4[Tq][32];
    __shared__ float pinv[Tq];

    int tid = threadIdx.x;
    size_t m0 = (size_t)blockIdx.x * 64;

    int r = tid >> 2;      // local row 0..63
    int h = tid & 3;       // quarter-row 0..3

    int wid  = tid >> 6;
    int lane = tid & 63;
    int l16  = lane & 15;
    int quad = lane >> 4;
    int mrow = (wid >> 1) * 32;   // 0 / 32
    int ncol = (wid & 1) * 64;    // 0 / 64
    int nt0  = (wid & 1) * 4;

    const bf16x8* wbase = reinterpret_cast<const bf16x8*>(wsw);
    bf16x8 bf[2][4];

    // issue x loads early (overlap with p/bias staging + barriers)
    const float4* xg = reinterpret_cast<const float4*>(x + (m0 + r) * 128) + h * 8;
    float4 xv[8];
    #pragma unroll
    for (int j = 0; j < 8; j++) xv[j] = xg[j];

    // stage p (8x128 fp32 = 256 float4) and bias (8x128 fp32 = 256 float4)
    reinterpret_cast<float4*>(&p4[0][0])[tid] = reinterpret_cast<const float4*>(p)[tid];
    reinterpret_cast<float4*>(&bxl[0][0])[tid] = reinterpret_cast<const float4*>(bx)[tid];

    // prefetch (t=0, n=0) B fragments during phase A
    #pragma unroll
    for (int kk = 0; kk < 4; kk++)
        bf[0][kk] = wbase[((size_t)(0 * 8 + nt0) * 4 + kk) * 64 + lane];

    __syncthreads();
    if (tid < Tq) {
        float s = 0.f;
        #pragma unroll
        for (int i = 0; i < 32; i++) {
            float4 v = p4[tid][i];
            s += v.x * v.x + v.y * v.y + v.z * v.z + v.w * v.w;
        }
        pinv[tid] = rsqrtf(s);
    }
    __syncthreads();

    // --- fp32 dots + |x|^2 over this thread's quarter-row, bf16 convert+store ---
    float dot[Tq];
    #pragma unroll
    for (int t = 0; t < Tq; t++) dot[t] = 0.f;
    float ssq = 0.f;
    #pragma unroll
    for (int j = 0; j < 8; j++) {
        float4 v = xv[j];
        ssq += v.x * v.x + v.y * v.y + v.z * v.z + v.w * v.w;
        #pragma unroll
        for (int t = 0; t < Tq; t++) {
            float4 pv = p4[t][h * 8 + j];
            dot[t] += v.x * pv.x + v.y * pv.y + v.z * pv.z + v.w * pv.w;
        }
    }
    #pragma unroll
    for (int jj = 0; jj < 4; jj++) {
        float4 v0 = xv[2 * jj], v1 = xv[2 * jj + 1];
        bf16x8 b;
        b[0] = (short)f2bf(v0.x); b[1] = (short)f2bf(v0.y);
        b[2] = (short)f2bf(v0.z); b[3] = (short)f2bf(v0.w);
        b[4] = (short)f2bf(v1.x); b[5] = (short)f2bf(v1.y);
        b[6] = (short)f2bf(v1.z); b[7] = (short)f2bf(v1.w);
        *reinterpret_cast<bf16x8*>(&xs[r][h * 32 + jj * 8]) = b;
    }
    // quad-reduce (lanes 4r..4r+3 adjacent within the wave)
    ssq += __shfl_xor(ssq, 1);
    ssq += __shfl_xor(ssq, 2);
    #pragma unroll
    for (int t = 0; t < Tq; t++) {
        dot[t] += __shfl_xor(dot[t], 1);
        dot[t] += __shfl_xor(dot[t], 2);
    }
    float xinv = rsqrtf(ssq);
    float c[Tq], mx = -1e30f;
    #pragma unroll
    for (int t = 0; t < Tq; t++) {
        c[t] = dot[t] * xinv * pinv[t];
        mx = fmaxf(mx, c[t]);
    }
    float sum = 0.f;
    #pragma unroll
    for (int t = 0; t < Tq; t++) { c[t] = __expf(c[t] - mx); sum += c[t]; }
    float inv = 1.f / sum;
    #pragma unroll
    for (int i = 0; i < 2; i++) simT[h * 2 + i][r] = c[h * 2 + i] * inv;
    __syncthreads();

    // --- GEMM phase: wave = 32 rows x 64 cols ---
    // A fragments: lane holds A[m=lane&15][k=quad*8+j]; reused across all 8 t.
    bf16x8 a[2][4];
    #pragma unroll
    for (int mt = 0; mt < 2; mt++)
        #pragma unroll
        for (int kk = 0; kk < 4; kk++)
            a[mt][kk] = *reinterpret_cast<const bf16x8*>(&xs[mrow + mt * 16 + l16][kk * 32 + quad * 8]);

    f32x4 o[2][4] = {};

    #pragma unroll 1
    for (int t = 0; t < Tq; t++) {
        #pragma unroll
        for (int n = 0; n < 4; n++) {       // compile-time n: o/bf statically indexed
            const int cur = n & 1;
            // prefetch fragments for (t, n+1) (n=3 wraps to (t+1, 0); t=7 unused)
            {
                const int n2 = (n + 1) & 3;
                int t2 = (n == 3) ? ((t + 1) & 7) : t;
                #pragma unroll
                for (int kk = 0; kk < 4; kk++)
                    bf[cur ^ 1][kk] = wbase[((size_t)(t2 * 8 + nt0 + n2) * 4 + kk) * 64 + lane];
            }
            // bias rides in the accumulator: y = bias + sum_k A*B (HW-free add)
            float bias = bxl[t][ncol + n * 16 + l16];
            f32x4 y0v = {bias, bias, bias, bias};
            f32x4 y[2] = {y0v, y0v};
            __builtin_amdgcn_s_setprio(1);
            #pragma unroll
            for (int kk = 0; kk < 4; kk++)
                #pragma unroll
                for (int mt = 0; mt < 2; mt++)
                    y[mt] = __builtin_amdgcn_mfma_f32_16x16x32_bf16(a[mt][kk], bf[cur][kk], y[mt], 0, 0, 0);
            __builtin_amdgcn_s_setprio(0);
            #pragma unroll
            for (int mt = 0; mt < 2; mt++) {
                f32x4 s4 = *reinterpret_cast<const f32x4*>(&simT[t][mrow + mt * 16 + quad * 4]);
                #pragma unroll
                for (int rr = 0; rr < 4; rr++)
                    o[mt][n][rr] += s4[rr] * y[mt][rr];
            }
        }
    }

    // --- epilogue: fp32 residual + store. C/D layout: col=lane&15, row=quad*4+reg ---
    // Non-temporal both sides: x re-read is the last use, out is never re-read.
    #pragma unroll
    for (int mt = 0; mt < 2; mt++)
        #pragma unroll
        for (int rr = 0; rr < 4; rr++) {
            size_t row = m0 + mrow + mt * 16 + quad * 4 + rr;
            #pragma unroll
            for (int n = 0; n < 4; n++) {
                size_t idx = row * 128 + ncol + n * 16 + l16;
                float xr = __builtin_nontemporal_load(&x[idx]);
                __builtin_nontemporal_store(xr + o[mt][n][rr], &out[idx]);
            }
        }
}

extern "C" void kernel_launch(void* const* d_in, const int* in_sizes, int n_in,
                              void* d_out, int out_size, void* d_ws, size_t ws_size,
                              hipStream_t stream) {
    const float* x   = (const float*)d_in[0];   // [B,S,D] fp32
    const float* Wx  = (const float*)d_in[1];   // [T,D,D] fp32
    const float* bx  = (const float*)d_in[2];   // [T,D]   fp32
    const float* p   = (const float*)d_in[3];   // [T,1,D] fp32
    float* out = (float*)d_out;

    unsigned short* wsw = (unsigned short*)d_ws;   // 131072 bf16 = 256 KB

    prep_kernel<<<dim3(64), dim3(256), 0, stream>>>(Wx, wsw);
    main_kernel<<<dim3(Mq / 64), dim3(256), 0, stream>>>(x, wsw, bx, p, out);
}

// Round 5
// 106.444 us; speedup vs baseline: 1.0763x; 1.0763x over previous
//
#include <hip/hip_runtime.h>

// Problem constants
#define Bq 32
#define Sq 2048
#define Dq 128
#define Tq 8
#define Mq (Bq * Sq)   // 65536 rows

typedef __attribute__((ext_vector_type(8))) short bf16x8;
typedef __attribute__((ext_vector_type(8))) unsigned short u16x8;
typedef __attribute__((ext_vector_type(4))) float f32x4;

static __device__ __forceinline__ unsigned short f2bf(float f) {
    unsigned int u = __float_as_uint(f);
    unsigned int r = (u + 0x7FFFu + ((u >> 16) & 1u)) >> 16;
    return (unsigned short)r;
}

// ---------------------------------------------------------------------------
// Kernel 1 (v3, coalesced): W [T,D,D] fp32 -> bf16 in MFMA B-fragment order.
// 64 blocks, one 16-row (t,n) group each = one contiguous 4KB slice of wsw.
// Reads fully coalesced (16 threads x 8 consecutive floats per row), writes
// fully coalesced (one 16B u16x8 per thread).
//   flat chunk = ((t*8+n)*4+kk)*64+lane  <-  W[16*(t*8+n) + (lane&15)]
//                                             [kk*32+(lane>>4)*8 .. +8)
// ---------------------------------------------------------------------------
__global__ __launch_bounds__(256) void prep_kernel(const float* __restrict__ W,
                                                   unsigned short* __restrict__ wsw) {
    __shared__ unsigned short lds[16][132];   // 132-short stride breaks bank alias
    int tid = threadIdx.x;
    int b = blockIdx.x;                        // 64 blocks = (t,n) pairs
    int rl = tid >> 4;                         // local row 0..15
    int c0 = (tid & 15) * 8;                   // 8 floats per thread
    const float4* src = reinterpret_cast<const float4*>(W + ((size_t)b * 16 + rl) * 128 + c0);
    #pragma unroll
    for (int q = 0; q < 2; q++) {
        float4 v = src[q];
        lds[rl][c0 + q * 4 + 0] = f2bf(v.x);
        lds[rl][c0 + q * 4 + 1] = f2bf(v.y);
        lds[rl][c0 + q * 4 + 2] = f2bf(v.z);
        lds[rl][c0 + q * 4 + 3] = f2bf(v.w);
    }
    __syncthreads();
    int lane = tid & 63;
    int kk   = tid >> 6;                       // 0..3
    int e    = lane & 15;
    int d    = kk * 32 + (lane >> 4) * 8;
    u16x8* dst = reinterpret_cast<u16x8*>(wsw) + (size_t)b * 256 + tid;
    *dst = *reinterpret_cast<const u16x8*>(&lds[e][d]);
}

// ---------------------------------------------------------------------------
// Kernel 2 (fused) — ROUND-1 CONFIGURATION RESTORED (best measured: 105.0us).
// Diagnosis after 4 rounds: main is HBM-STARVED, not latency-bound — the
// harness's two 256MiB re-poison fills run concurrently at ~6.1 TB/s; main
// gets ~1.5 TB/s; fills+main ~= 7.5 TB/s = device saturation. main's wall
// time = its byte count (57-65MB, already at the 64MB x-read+out-write floor)
// divided by leftover bandwidth. No intra-kernel restructuring changes that
// (rounds 2-4: 43-47us invariant across 4 structures). So: best-measured
// shape, minimal bytes, nothing speculative.
//   128-row tiles, 512 blocks (2/CU), 64x64 wave tiles.
//   phase A: stage x -> bf16 LDS (2 threads/row, fp32 in registers),
//            fp32 p-dots + |x|^2 inline, pair shuffle-reduce, softmax->simT.
//   phase B: MFMA GEMM vs pre-swizzled W, 2-deep B-fragment double buffer,
//            bias rides in the MFMA C-operand, s_setprio around MFMA cluster.
//   epilogue: out = x + sum_t sim*(y+bias); nontemporal on both sides.
// ---------------------------------------------------------------------------
__global__ __launch_bounds__(256, 2) void main_kernel(const float* __restrict__ x,
                                                      const unsigned short* __restrict__ wsw,
                                                      const float* __restrict__ bx,
                                                      const float* __restrict__ p,
                                                      float* __restrict__ out) {
    __shared__ unsigned short xs[128][136];  // +16B pad: row stride 272B (16B-aligned)
    __shared__ float simT[Tq][128];
    __shared__ float bxl[Tq][128];
    __shared__ float4 p4[Tq][32];
    __shared__ float pinv[Tq];

    int tid = threadIdx.x;
    size_t m0 = (size_t)blockIdx.x * 128;

    int r = tid >> 1;      // local row 0..127
    int h = tid & 1;       // half-row 0/1

    // issue x loads early (overlap with p/bias staging + barriers)
    const float4* xg = reinterpret_cast<const float4*>(x + (m0 + r) * 128) + h * 16;
    float4 xv[16];
    #pragma unroll
    for (int j = 0; j < 16; j++) xv[j] = xg[j];

    // stage p (8x128 fp32) and bias (8x128 fp32)
    reinterpret_cast<float4*>(&p4[0][0])[tid] = reinterpret_cast<const float4*>(p)[tid];
    reinterpret_cast<float4*>(&bxl[0][0])[tid] = reinterpret_cast<const float4*>(bx)[tid];
    __syncthreads();
    if (tid < Tq) {
        float s = 0.f;
        #pragma unroll
        for (int i = 0; i < 32; i++) {
            float4 v = p4[tid][i];
            s += v.x * v.x + v.y * v.y + v.z * v.z + v.w * v.w;
        }
        pinv[tid] = rsqrtf(s);
    }
    __syncthreads();

    // --- fp32 dots + |x|^2 over this thread's half-row, bf16 convert+store ---
    float dot[Tq];
    #pragma unroll
    for (int t = 0; t < Tq; t++) dot[t] = 0.f;
    float ssq = 0.f;
    #pragma unroll
    for (int j = 0; j < 16; j++) {
        float4 v = xv[j];
        ssq += v.x * v.x + v.y * v.y + v.z * v.z + v.w * v.w;
        #pragma unroll
        for (int t = 0; t < Tq; t++) {
            float4 pv = p4[t][h * 16 + j];
            dot[t] += v.x * pv.x + v.y * pv.y + v.z * pv.z + v.w * pv.w;
        }
    }
    #pragma unroll
    for (int jj = 0; jj < 8; jj++) {
        float4 v0 = xv[2 * jj], v1 = xv[2 * jj + 1];
        bf16x8 b;
        b[0] = (short)f2bf(v0.x); b[1] = (short)f2bf(v0.y);
        b[2] = (short)f2bf(v0.z); b[3] = (short)f2bf(v0.w);
        b[4] = (short)f2bf(v1.x); b[5] = (short)f2bf(v1.y);
        b[6] = (short)f2bf(v1.z); b[7] = (short)f2bf(v1.w);
        *reinterpret_cast<bf16x8*>(&xs[r][h * 64 + jj * 8]) = b;
    }
    // pair-reduce (lanes 2r, 2r+1 adjacent)
    ssq += __shfl_xor(ssq, 1);
    #pragma unroll
    for (int t = 0; t < Tq; t++) dot[t] += __shfl_xor(dot[t], 1);
    float xinv = rsqrtf(ssq);
    float c[Tq], mx = -1e30f;
    #pragma unroll
    for (int t = 0; t < Tq; t++) {
        c[t] = dot[t] * xinv * pinv[t];
        mx = fmaxf(mx, c[t]);
    }
    float sum = 0.f;
    #pragma unroll
    for (int t = 0; t < Tq; t++) { c[t] = __expf(c[t] - mx); sum += c[t]; }
    float inv = 1.f / sum;
    #pragma unroll
    for (int i = 0; i < 4; i++) simT[h * 4 + i][r] = c[h * 4 + i] * inv;
    __syncthreads();

    // --- GEMM phase ---
    int wid  = tid >> 6;
    int lane = tid & 63;
    int l16  = lane & 15;
    int quad = lane >> 4;
    int mrow = (wid >> 1) * 64;
    int ncol = (wid & 1) * 64;
    int nt0  = ncol >> 4;

    // A fragments: lane holds A[m=lane&15][k=quad*8+j]; reused across all 8 t.
    bf16x8 a[4][4];
    #pragma unroll
    for (int mt = 0; mt < 4; mt++)
        #pragma unroll
        for (int k = 0; k < 4; k++)
            a[mt][k] = *reinterpret_cast<const bf16x8*>(&xs[mrow + mt * 16 + l16][k * 32 + quad * 8]);

    f32x4 o[4][4] = {};

    const bf16x8* wbase = reinterpret_cast<const bf16x8*>(wsw);
    bf16x8 bf[2][4];
    #pragma unroll
    for (int k = 0; k < 4; k++)
        bf[0][k] = wbase[((size_t)(0 * 8 + nt0) * 4 + k) * 64 + lane];

    #pragma unroll 1
    for (int t = 0; t < Tq; t++) {
        f32x4 s[4];
        #pragma unroll
        for (int mt = 0; mt < 4; mt++)
            s[mt] = *reinterpret_cast<const f32x4*>(&simT[t][mrow + mt * 16 + quad * 4]);

        #pragma unroll
        for (int n = 0; n < 4; n++) {       // compile-time n: o[][] stays in VGPRs
            const int cur = n & 1;
            // prefetch fragments for (t, n+1) (wraps to (t+1,0); t=7,n=3 wraps to t=0, unused)
            {
                const int n2 = (n + 1) & 3;
                int t2 = (n == 3) ? ((t + 1) & 7) : t;
                #pragma unroll
                for (int k = 0; k < 4; k++)
                    bf[cur ^ 1][k] = wbase[((size_t)(t2 * 8 + nt0 + n2) * 4 + k) * 64 + lane];
            }
            // bias rides in the accumulator: y = bias + sum_k A*B (HW-free add)
            float bias = bxl[t][ncol + n * 16 + l16];
            f32x4 y0 = {bias, bias, bias, bias};
            f32x4 y[4] = {y0, y0, y0, y0};
            __builtin_amdgcn_s_setprio(1);
            #pragma unroll
            for (int k = 0; k < 4; k++)
                #pragma unroll
                for (int mt = 0; mt < 4; mt++)
                    y[mt] = __builtin_amdgcn_mfma_f32_16x16x32_bf16(a[mt][k], bf[cur][k], y[mt], 0, 0, 0);
            __builtin_amdgcn_s_setprio(0);
            #pragma unroll
            for (int mt = 0; mt < 4; mt++)
                #pragma unroll
                for (int rr = 0; rr < 4; rr++)
                    o[mt][n][rr] += s[mt][rr] * y[mt][rr];
        }
    }

    // --- epilogue: fp32 residual + store. C/D layout: col=lane&15, row=quad*4+reg ---
    // Non-temporal on both sides: x re-read is the last use, out is never re-read.
    #pragma unroll
    for (int mt = 0; mt < 4; mt++)
        #pragma unroll
        for (int rr = 0; rr < 4; rr++) {
            size_t row = m0 + mrow + mt * 16 + quad * 4 + rr;
            #pragma unroll
            for (int n = 0; n < 4; n++) {
                size_t idx = row * 128 + ncol + n * 16 + l16;
                float xr = __builtin_nontemporal_load(&x[idx]);
                __builtin_nontemporal_store(xr + o[mt][n][rr], &out[idx]);
            }
        }
}

extern "C" void kernel_launch(void* const* d_in, const int* in_sizes, int n_in,
                              void* d_out, int out_size, void* d_ws, size_t ws_size,
                              hipStream_t stream) {
    const float* x   = (const float*)d_in[0];   // [B,S,D] fp32
    const float* Wx  = (const float*)d_in[1];   // [T,D,D] fp32
    const float* bx  = (const float*)d_in[2];   // [T,D]   fp32
    const float* p   = (const float*)d_in[3];   // [T,1,D] fp32
    float* out = (float*)d_out;

    unsigned short* wsw = (unsigned short*)d_ws;   // 131072 bf16 = 256 KB

    prep_kernel<<<dim3(64), dim3(256), 0, stream>>>(Wx, wsw);
    main_kernel<<<dim3(Mq / 128), dim3(256), 0, stream>>>(x, wsw, bx, p, out);
}